// Round 11
// baseline (5022.878 us; speedup 1.0000x reference)
//
#include <hip/hip_runtime.h>
#include <hip/hip_bf16.h>
#include <cstdint>

#define T_ 512
#define B_ 1024
#define D_ 6
#define H_ 128
#define CH_ 8   // chunk timesteps
#define NBLK 256

typedef _Float16 f16;
typedef _Float16 f16x8 __attribute__((ext_vector_type(8)));
typedef float f32x4 __attribute__((ext_vector_type(4)));

// branch-free erf (Abramowitz-Stegun 7.1.26, max abs err 1.5e-7)
__device__ __forceinline__ float erf_f(float x) {
    float ax = fabsf(x);
    float t = __builtin_amdgcn_rcpf(fmaf(0.3275911f, ax, 1.f));
    float p = fmaf(t, 1.061405429f, -1.453152027f);
    p = fmaf(t, p, 1.421413741f);
    p = fmaf(t, p, -0.284496736f);
    p = fmaf(t, p, 0.254829592f);
    p = p * t;
    float e = __builtin_amdgcn_exp2f(-ax * ax * 1.4426950408889634f);
    float r = 1.f - p * e;
    return copysignf(r, x);
}
__device__ __forceinline__ float gelu_f(float x) {
    return 0.5f * x * (1.f + erf_f(x * 0.7071067811865476f));
}
__device__ __forceinline__ float sig_f(float x) {
    return __builtin_amdgcn_rcpf(1.f + __builtin_amdgcn_exp2f(-1.4426950408889634f * x));
}
__device__ __forceinline__ float tanh_f(float x) {
    return 2.f * sig_f(2.f * x) - 1.f;
}
__device__ __forceinline__ f16x8 load8cvt(const float* p) {
    float4 a = ((const float4*)p)[0];
    float4 b = ((const float4*)p)[1];
    f16x8 r = { (f16)a.x, (f16)a.y, (f16)a.z, (f16)a.w,
                (f16)b.x, (f16)b.y, (f16)b.z, (f16)b.w };
    return r;
}
// LDS tiles: row-major [rows][128] f16, 256B row stride, 16B-chunk XOR swizzle
__device__ __forceinline__ f16x8 lds_rd8(const f16* base, int row, int cb) {
    const char* p = (const char*)base + row * 256 + (cb ^ ((row & 7) << 4));
    return *(const f16x8*)p;
}
__device__ __forceinline__ void lds_wr1(f16* base, int row, int col, f16 v) {
    char* p = (char*)base + row * 256 + ((col * 2) ^ ((row & 7) << 4));
    *(f16*)p = v;
}
// ZX tile: [32 rows][512 cols] f16, 1024B row stride, same XOR swizzle
__device__ __forceinline__ void zx_wr(f16* base, int row, int col, f16 v) {
    char* p = (char*)base + row * 1024 + ((col * 2) ^ ((row & 7) << 4));
    *(f16*)p = v;
}
__device__ __forceinline__ float zx_rd(const f16* base, int row, int col) {
    const char* p = (const char*)base + row * 1024 + ((col * 2) ^ ((row & 7) << 4));
    return (float)*(const f16*)p;
}

// ---------------------------------------------------------------------------
// K1: block-specialized producer/consumer. 512 blocks x 512 threads,
// 2 blocks/CU (58KB LDS, <=128 VGPR each) -> all co-resident by capacity.
//  blocks 0..255   (producer p):  R7-proven conv stack + lstm0, chunked;
//     per chunk: P0 convL0 | P1-P3 conv MFMA (B streamed) | P4 zgemm ZX0 |
//     8 lstm0 slots -> YH | flush YH -> ys | threadfence | flag[p]=k+1 (release)
//  blocks 256..511 (consumer p):  chunked lstm1, lagging one chunk;
//     per chunk: acquire-spin flag[p]>k | zgemm ZX1 (A straight from global ys,
//     B=Wih1 streamed) | 8 lstm1 slots. End: hfin.
// Each path keeps ONE whh resident (64 frag regs) - inside the proven
// 128-VGPR budget (R7). Producers never wait on consumers: no deadlock mode,
// worst case degrades to serial (R7-equivalent).
// ---------------------------------------------------------------------------
__global__ __launch_bounds__(512) void fused_pc_k(
    const float* __restrict__ src,
    const float* __restrict__ w0p, const float* __restrict__ b0p,
    const float* __restrict__ w1p, const float* __restrict__ b1p,
    const float* __restrict__ w2p, const float* __restrict__ b2p,
    const float* __restrict__ w3p, const float* __restrict__ b3p,
    const float* __restrict__ posp,
    const float* __restrict__ Wih0, const float* __restrict__ Whh0,
    const float* __restrict__ bih0, const float* __restrict__ bhh0,
    const float* __restrict__ Wih1, const float* __restrict__ Whh1,
    const float* __restrict__ bih1, const float* __restrict__ bhh1,
    f16* __restrict__ ys, int* __restrict__ flags,
    float* __restrict__ hfin)
{
    __shared__ __align__(16) char smem[59392];   // union: prod 58KB / cons 34KB

    const int tid = threadIdx.x;
    const int lane = tid & 63, wid = tid >> 6;
    const int l16 = lane & 15, hi = lane >> 4;
    const int mycol = wid * 16 + l16;
    const bool producer = (int)blockIdx.x < NBLK;
    const int p = producer ? blockIdx.x : blockIdx.x - NBLK;
    const int bb0 = p * 4;

    // one LSTM step (h-side MFMA + pointwise); t parity selects HL buffer
    auto lstep = [&](f16* HLd, int t, const f16x8 (&whf)[4][4],
                     const float (&bg)[4], const f16* ZXp, int it,
                     float& cc, float& hh, f16* yout) {
        f16x8 ha[4];
#pragma unroll
        for (int ki = 0; ki < 4; ++ki)
            ha[ki] = lds_rd8(HLd + (t & 1) * 512, l16 >> 2, ki * 64 + hi * 16);
        f32x4 acc[4];
#pragma unroll
        for (int g = 0; g < 4; ++g) {
            f32x4 bv = { bg[g], bg[g], bg[g], bg[g] };
            acc[g] = bv;
        }
#pragma unroll
        for (int ki = 0; ki < 4; ++ki)
#pragma unroll
            for (int g = 0; g < 4; ++g)
                acc[g] = __builtin_amdgcn_mfma_f32_16x16x32_f16(ha[ki], whf[g][ki], acc[g], 0, 0, 0);
        float zi = acc[0][0] + zx_rd(ZXp, it * 4 + hi, 0 + mycol);
        float zf = acc[1][0] + zx_rd(ZXp, it * 4 + hi, 128 + mycol);
        float zg = acc[2][0] + zx_rd(ZXp, it * 4 + hi, 256 + mycol);
        float zo = acc[3][0] + zx_rd(ZXp, it * 4 + hi, 384 + mycol);
        cc = sig_f(zf) * cc + sig_f(zi) * tanh_f(zg);
        hh = sig_f(zo) * tanh_f(cc);
        lds_wr1(HLd + ((t + 1) & 1) * 512, hi, mycol, (f16)hh);
        if (yout) lds_wr1(yout, it * 4 + hi, mycol, (f16)hh);
    };

    if (producer) {
        f16* XA0 = (f16*)smem;                 // 8KB
        f16* XA1 = (f16*)(smem + 8192);        // 8KB
        f16* ZX0 = (f16*)(smem + 16384);       // 32KB
        f16* YH  = (f16*)(smem + 49152);       // 8KB
        f16* HL0 = (f16*)(smem + 57344);       // 2KB (2 x 4x128)

        // lstm0 h-side frags resident (64 regs) - R7-proven budget
        f16x8 whh0[4][4];
        float bg0[4];
#pragma unroll
        for (int g = 0; g < 4; ++g) {
            int n = g * 128 + mycol;
            bg0[g] = bih0[n] + bhh0[n];
#pragma unroll
            for (int ki = 0; ki < 4; ++ki)
                whh0[g][ki] = load8cvt(Whh0 + n * 128 + ki * 32 + hi * 8);
        }
        const int col0 = tid & 127;
        const int r0 = tid >> 7;
        float w0c[6], b0c;
#pragma unroll
        for (int k = 0; k < 6; ++k) w0c[k] = w0p[col0 * 6 + k];
        b0c = b0p[col0];
        const float b1c = b1p[mycol], b2c = b2p[mycol], b3c = b3p[mycol];
        for (int i = tid; i < 2 * 512; i += 512) HL0[i] = (f16)0.f;

        float c0 = 0.f, h0 = 0.f;
        __syncthreads();

        auto conv_mfma = [&](const f16* Xin, f16* Xout, const float* Wg, float bc, int t0pos) {
            f16x8 bf[4];
#pragma unroll
            for (int ki = 0; ki < 4; ++ki)
                bf[ki] = load8cvt(Wg + mycol * 128 + ki * 32 + hi * 8);
#pragma unroll
            for (int mt = 0; mt < 2; ++mt) {
                f16x8 af[4];
#pragma unroll
                for (int ki = 0; ki < 4; ++ki)
                    af[ki] = lds_rd8(Xin, mt * 16 + l16, ki * 64 + hi * 16);
                f32x4 acc = { bc, bc, bc, bc };
#pragma unroll
                for (int ki = 0; ki < 4; ++ki)
                    acc = __builtin_amdgcn_mfma_f32_16x16x32_f16(af[ki], bf[ki], acc, 0, 0, 0);
                float pv = 0.f;
                if (t0pos >= 0) pv = posp[(t0pos + mt * 4 + hi) * 128 + mycol];
#pragma unroll
                for (int j = 0; j < 4; ++j)
                    lds_wr1(Xout, mt * 16 + hi * 4 + j, mycol, (f16)(gelu_f(acc[j]) + pv));
            }
        };

        for (int k = 0; k < T_ / CH_; ++k) {
            const int t0 = k * CH_;
            // P0: conv layer0 (VALU) -> XA0
            {
                const float2* sp0 = (const float2*)src + ((size_t)(bb0 + r0) * T_ + t0) * 3;
#pragma unroll
                for (int it = 0; it < CH_; ++it) {
                    float2 a = sp0[it * 3 + 0], b = sp0[it * 3 + 1], c2 = sp0[it * 3 + 2];
                    float acc = b0c;
                    acc = fmaf(a.x, w0c[0], acc);
                    acc = fmaf(a.y, w0c[1], acc);
                    acc = fmaf(b.x, w0c[2], acc);
                    acc = fmaf(b.y, w0c[3], acc);
                    acc = fmaf(c2.x, w0c[4], acc);
                    acc = fmaf(c2.y, w0c[5], acc);
                    lds_wr1(XA0, it * 4 + r0, col0, (f16)gelu_f(acc));
                }
            }
            __syncthreads();
            conv_mfma(XA0, XA1, w1p, b1c, -1);
            __syncthreads();
            conv_mfma(XA1, XA0, w2p, b2c, -1);
            __syncthreads();
            conv_mfma(XA0, XA1, w3p, b3c, t0);   // + pos_embed
            __syncthreads();
            // P4: ZX0 = x @ Wih0^T (B streamed, R7-proven)
            {
                f16x8 af[2][4];
#pragma unroll
                for (int mt = 0; mt < 2; ++mt)
#pragma unroll
                    for (int ki = 0; ki < 4; ++ki)
                        af[mt][ki] = lds_rd8(XA1, mt * 16 + l16, ki * 64 + hi * 16);
#pragma unroll
                for (int nt = 0; nt < 4; ++nt) {
                    const int n = wid * 64 + nt * 16 + l16;
                    f16x8 bf[4];
#pragma unroll
                    for (int ki = 0; ki < 4; ++ki)
                        bf[ki] = load8cvt(Wih0 + n * 128 + ki * 32 + hi * 8);
                    f32x4 za0 = { 0.f, 0.f, 0.f, 0.f };
                    f32x4 za1 = { 0.f, 0.f, 0.f, 0.f };
#pragma unroll
                    for (int ki = 0; ki < 4; ++ki) {
                        za0 = __builtin_amdgcn_mfma_f32_16x16x32_f16(af[0][ki], bf[ki], za0, 0, 0, 0);
                        za1 = __builtin_amdgcn_mfma_f32_16x16x32_f16(af[1][ki], bf[ki], za1, 0, 0, 0);
                    }
#pragma unroll
                    for (int j = 0; j < 4; ++j) {
                        zx_wr(ZX0, hi * 4 + j, wid * 64 + nt * 16 + l16, (f16)za0[j]);
                        zx_wr(ZX0, 16 + hi * 4 + j, wid * 64 + nt * 16 + l16, (f16)za1[j]);
                    }
                    __builtin_amdgcn_sched_barrier(0);
                }
            }
            __syncthreads();
            // P5 x8: lstm0 slots -> YH
            for (int it = 0; it < CH_; ++it) {
                lstep(HL0, t0 + it, whh0, bg0, ZX0, it, c0, h0, YH);
                __syncthreads();
            }
            // flush YH -> ys (coalesced), publish chunk
            {
                int tau = tid >> 4, cw8 = tid & 15;
                f16x8 v = lds_rd8(YH, tau, cw8 * 16);
                *(f16x8*)(ys + (size_t)(t0 + (tau >> 2)) * (B_ * H_) +
                          (size_t)(bb0 + (tau & 3)) * H_ + cw8 * 8) = v;
            }
            __threadfence();
            __syncthreads();
            if (tid == 0)
                __hip_atomic_store(&flags[p], k + 1, __ATOMIC_RELEASE,
                                   __HIP_MEMORY_SCOPE_AGENT);
        }
    } else {
        f16* ZX1 = (f16*)smem;                 // 32KB
        f16* HL1 = (f16*)(smem + 32768);       // 2KB

        // lstm1 h-side frags resident (64 regs)
        f16x8 whh1[4][4];
        float bg1[4];
#pragma unroll
        for (int g = 0; g < 4; ++g) {
            int n = g * 128 + mycol;
            bg1[g] = bih1[n] + bhh1[n];
#pragma unroll
            for (int ki = 0; ki < 4; ++ki)
                whh1[g][ki] = load8cvt(Whh1 + n * 128 + ki * 32 + hi * 8);
        }
        for (int i = tid; i < 2 * 512; i += 512) HL1[i] = (f16)0.f;
        float c1 = 0.f, h1 = 0.f;
        __syncthreads();

        for (int k = 0; k < T_ / CH_; ++k) {
            const int t0 = k * CH_;
            // acquire chunk k from producer p
            if (tid == 0) {
                while (__hip_atomic_load(&flags[p], __ATOMIC_ACQUIRE,
                                         __HIP_MEMORY_SCOPE_AGENT) < k + 1)
                    __builtin_amdgcn_s_sleep(8);
            }
            __syncthreads();
            // ZX1 = ys_chunk @ Wih1^T (A straight from global, B streamed)
            {
                f16x8 af[2][4];
#pragma unroll
                for (int mt = 0; mt < 2; ++mt) {
                    const int tau = mt * 16 + l16;
                    const f16* ap = ys + (size_t)(t0 + (tau >> 2)) * (B_ * H_) +
                                    (size_t)(bb0 + (tau & 3)) * H_;
#pragma unroll
                    for (int ki = 0; ki < 4; ++ki)
                        af[mt][ki] = *(const f16x8*)(ap + ki * 32 + hi * 8);
                }
#pragma unroll
                for (int nt = 0; nt < 4; ++nt) {
                    const int n = wid * 64 + nt * 16 + l16;
                    f16x8 bf[4];
#pragma unroll
                    for (int ki = 0; ki < 4; ++ki)
                        bf[ki] = load8cvt(Wih1 + n * 128 + ki * 32 + hi * 8);
                    f32x4 za0 = { 0.f, 0.f, 0.f, 0.f };
                    f32x4 za1 = { 0.f, 0.f, 0.f, 0.f };
#pragma unroll
                    for (int ki = 0; ki < 4; ++ki) {
                        za0 = __builtin_amdgcn_mfma_f32_16x16x32_f16(af[0][ki], bf[ki], za0, 0, 0, 0);
                        za1 = __builtin_amdgcn_mfma_f32_16x16x32_f16(af[1][ki], bf[ki], za1, 0, 0, 0);
                    }
#pragma unroll
                    for (int j = 0; j < 4; ++j) {
                        zx_wr(ZX1, hi * 4 + j, wid * 64 + nt * 16 + l16, (f16)za0[j]);
                        zx_wr(ZX1, 16 + hi * 4 + j, wid * 64 + nt * 16 + l16, (f16)za1[j]);
                    }
                    __builtin_amdgcn_sched_barrier(0);
                }
            }
            __syncthreads();
            for (int it = 0; it < CH_; ++it) {
                lstep(HL1, t0 + it, whh1, bg1, ZX1, it, c1, h1, nullptr);
                __syncthreads();
            }
        }
        hfin[(size_t)(bb0 + hi) * H_ + mycol] = h1;
    }
}

// ---------------------------------------------------------------------------
// K2: head — LayerNorm + Linear(128->32) + GELU + Linear(32->8). 4 rows/block.
// ---------------------------------------------------------------------------
__global__ __launch_bounds__(256) void head_k(
    const float* __restrict__ hfin,
    const float* __restrict__ lng, const float* __restrict__ lnb,
    const float* __restrict__ hw1, const float* __restrict__ hb1,
    const float* __restrict__ hw2, const float* __restrict__ hb2,
    float* __restrict__ outp)
{
    __shared__ float HN[4][128];
    __shared__ float G[4][32];
    const int tid = threadIdx.x, lane = tid & 63, wid = tid >> 6;
    const int b = blockIdx.x * 4 + wid;
    float v0 = hfin[b * 128 + lane], v1 = hfin[b * 128 + 64 + lane];
    float s = v0 + v1;
#pragma unroll
    for (int m = 1; m < 64; m <<= 1) s += __shfl_xor(s, m);
    float mu = s * (1.f / 128.f);
    float d0 = v0 - mu, d1 = v1 - mu;
    float q = d0 * d0 + d1 * d1;
#pragma unroll
    for (int m = 1; m < 64; m <<= 1) q += __shfl_xor(q, m);
    float rs = rsqrtf(q * (1.f / 128.f) + 1e-5f);
    HN[wid][lane] = d0 * rs * lng[lane] + lnb[lane];
    HN[wid][64 + lane] = d1 * rs * lng[64 + lane] + lnb[64 + lane];
    __syncthreads();
    if (tid < 128) {
        int row = tid >> 5, o = tid & 31;
        float a = hb1[o];
#pragma unroll 4
        for (int k = 0; k < 128; ++k) a = fmaf(HN[row][k], hw1[o * 128 + k], a);
        G[row][o] = gelu_f(a);
    }
    __syncthreads();
    if (tid < 32) {
        int row = tid >> 3, oo = tid & 7;
        float a = hb2[oo];
#pragma unroll
        for (int k = 0; k < 32; ++k) a = fmaf(G[row][k], hw2[oo * 32 + k], a);
        outp[(size_t)(blockIdx.x * 4 + row) * 8 + oo] = a;
    }
}

extern "C" void kernel_launch(void* const* d_in, const int* in_sizes, int n_in,
                              void* d_out, int out_size, void* d_ws, size_t ws_size,
                              hipStream_t stream) {
    (void)in_sizes; (void)n_in; (void)out_size; (void)ws_size;
    const float* src  = (const float*)d_in[0];
    const float* w0   = (const float*)d_in[1];
    const float* b0   = (const float*)d_in[2];
    const float* w1   = (const float*)d_in[3];
    const float* b1   = (const float*)d_in[4];
    const float* w2   = (const float*)d_in[5];
    const float* b2   = (const float*)d_in[6];
    const float* w3   = (const float*)d_in[7];
    const float* b3   = (const float*)d_in[8];
    const float* pos  = (const float*)d_in[9];
    const float* Wih0 = (const float*)d_in[10];
    const float* Whh0 = (const float*)d_in[11];
    const float* bih0 = (const float*)d_in[12];
    const float* bhh0 = (const float*)d_in[13];
    const float* Wih1 = (const float*)d_in[14];
    const float* Whh1 = (const float*)d_in[15];
    const float* bih1 = (const float*)d_in[16];
    const float* bhh1 = (const float*)d_in[17];
    const float* lng  = (const float*)d_in[18];
    const float* lnb  = (const float*)d_in[19];
    const float* hw1  = (const float*)d_in[20];
    const float* hb1  = (const float*)d_in[21];
    const float* hw2  = (const float*)d_in[22];
    const float* hb2  = (const float*)d_in[23];
    float* outp = (float*)d_out;

    f16*   ysbuf = (f16*)d_ws;                                  // 128MB
    float* hfin  = (float*)((char*)d_ws + (size_t)134217728);   // 512KB
    int*   flags = (int*)((char*)d_ws + (size_t)134742016);     // 1KB

    hipMemsetAsync(flags, 0, 1024, stream);
    fused_pc_k<<<dim3(2 * NBLK), dim3(512), 0, stream>>>(
        src, w0, b0, w1, b1, w2, b2, w3, b3, pos,
        Wih0, Whh0, bih0, bhh0, Wih1, Whh1, bih1, bhh1,
        ysbuf, flags, hfin);
    head_k<<<dim3(256), dim3(256), 0, stream>>>(
        hfin, lng, lnb, hw1, hb1, hw2, hb2, outp);
}

// Round 12
// 1091.583 us; speedup vs baseline: 4.6015x; 4.6015x over previous
//
#include <hip/hip_runtime.h>
#include <hip/hip_bf16.h>
#include <cstdint>

#define T_ 512
#define B_ 1024
#define D_ 6
#define H_ 128
#define CH_ 8   // chunk timesteps

typedef _Float16 f16;
typedef _Float16 f16x8 __attribute__((ext_vector_type(8)));
typedef float f32x4 __attribute__((ext_vector_type(4)));

// branch-free erf (Abramowitz-Stegun 7.1.26, max abs err 1.5e-7)
__device__ __forceinline__ float erf_f(float x) {
    float ax = fabsf(x);
    float t = __builtin_amdgcn_rcpf(fmaf(0.3275911f, ax, 1.f));
    float p = fmaf(t, 1.061405429f, -1.453152027f);
    p = fmaf(t, p, 1.421413741f);
    p = fmaf(t, p, -0.284496736f);
    p = fmaf(t, p, 0.254829592f);
    p = p * t;
    float e = __builtin_amdgcn_exp2f(-ax * ax * 1.4426950408889634f);
    float r = 1.f - p * e;
    return copysignf(r, x);
}
__device__ __forceinline__ float gelu_f(float x) {
    return 0.5f * x * (1.f + erf_f(x * 0.7071067811865476f));
}
__device__ __forceinline__ float sig_f(float x) {
    return __builtin_amdgcn_rcpf(1.f + __builtin_amdgcn_exp2f(-1.4426950408889634f * x));
}
__device__ __forceinline__ float tanh_f(float x) {
    return 2.f * sig_f(2.f * x) - 1.f;
}
__device__ __forceinline__ f16x8 load8cvt(const float* p) {
    float4 a = ((const float4*)p)[0];
    float4 b = ((const float4*)p)[1];
    f16x8 r = { (f16)a.x, (f16)a.y, (f16)a.z, (f16)a.w,
                (f16)b.x, (f16)b.y, (f16)b.z, (f16)b.w };
    return r;
}
// LDS tiles: row-major [rows][128] f16, 256B row stride, 16B-chunk XOR swizzle
__device__ __forceinline__ f16x8 lds_rd8(const f16* base, int row, int cb) {
    const char* p = (const char*)base + row * 256 + (cb ^ ((row & 7) << 4));
    return *(const f16x8*)p;
}
__device__ __forceinline__ void lds_wr1(f16* base, int row, int col, f16 v) {
    char* p = (char*)base + row * 256 + ((col * 2) ^ ((row & 7) << 4));
    *(f16*)p = v;
}
// ZX tile: [32 rows][512 cols] f16, 1024B row stride, same XOR swizzle
__device__ __forceinline__ void zx_wr(f16* base, int row, int col, f16 v) {
    char* p = (char*)base + row * 1024 + ((col * 2) ^ ((row & 7) << 4));
    *(f16*)p = v;
}
__device__ __forceinline__ float zx_rd(const f16* base, int row, int col) {
    const char* p = (const char*)base + row * 1024 + ((col * 2) ^ ((row & 7) << 4));
    return (float)*(const f16*)p;
}

// ---------------------------------------------------------------------------
// K1: FUSED conv stack + LSTM layer 0, CHUNKED — EXACT R7 (proven 780us,
// FETCH 24MB, no spills). Register model (R4-R11): 512-thr blocks get
// 128 arch-VGPR + <=128 AGPR fragments per lane; ONE resident weight-frag
// matrix (whh0, 64) fits, everything else must be streamed phase-locally.
// ---------------------------------------------------------------------------
__global__ __launch_bounds__(512) void fused_conv_lstm0_k(
    const float* __restrict__ src,
    const float* __restrict__ w0p, const float* __restrict__ b0p,
    const float* __restrict__ w1p, const float* __restrict__ b1p,
    const float* __restrict__ w2p, const float* __restrict__ b2p,
    const float* __restrict__ w3p, const float* __restrict__ b3p,
    const float* __restrict__ posp,
    const float* __restrict__ Wih, const float* __restrict__ Whh,
    const float* __restrict__ bih, const float* __restrict__ bhh,
    f16* __restrict__ ys)
{
    __shared__ f16 CW[3 * 8 * 4 * 512];   // 96KB conv w1..w3 B-fragments
    __shared__ f16 XA0[32 * 128];         // 8KB token tile ping
    __shared__ f16 XA1[32 * 128];         // 8KB token tile pong
    __shared__ f16 ZX[32 * 512];          // 32KB z_x chunk (f16)
    __shared__ f16 YH[32 * 128];          // 8KB h history (chunk)
    __shared__ f16 HL[2][4 * 128];        // 2KB h double-buffer (4 real rows)

    const int tid = threadIdx.x;
    const int lane = tid & 63, wid = tid >> 6;
    const int l16 = lane & 15, hi = lane >> 4;
    const int bb0 = blockIdx.x * 4;
    const int mycol = wid * 16 + l16;

    // h-side weight frags only (wave owns col g*128+mycol): 64 regs
    f16x8 whh[4][4];
    float biasg[4];
#pragma unroll
    for (int g = 0; g < 4; ++g) {
        int n = g * 128 + mycol;
        biasg[g] = bih[n] + bhh[n];
#pragma unroll
        for (int ki = 0; ki < 4; ++ki)
            whh[g][ki] = load8cvt(Whh + n * 128 + ki * 32 + hi * 8);
    }

    // conv layer0 per-thread slice + conv biases
    const int col0 = tid & 127;
    const int r0 = tid >> 7;
    float w0c[6], b0c;
#pragma unroll
    for (int k = 0; k < 6; ++k) w0c[k] = w0p[col0 * 6 + k];
    b0c = b0p[col0];
    const float b1c = b1p[mycol], b2c = b2p[mycol], b3c = b3p[mycol];

    // stage conv weights w1..w3 into CW as B-fragments
    {
        const float* wp[3] = { w1p, w2p, w3p };
        for (int i = tid; i < 6144; i += 512) {
            int ln = i & 63, ki = (i >> 6) & 3, cg = (i >> 8) & 7, L = i >> 11;
            f16x8 v = load8cvt(wp[L] + (cg * 16 + (ln & 15)) * 128 + ki * 32 + (ln >> 4) * 8);
            *(f16x8*)(CW + i * 8) = v;
        }
    }
    for (int i = tid; i < 2 * 4 * 128; i += 512) ((f16*)HL)[i] = (f16)0.f;

    float c = 0.f, h = 0.f;
    __syncthreads();

    auto conv_mfma = [&](const f16* Xin, f16* Xout, int L, float bc, int t0pos) {
        f16x8 bf[4];
#pragma unroll
        for (int ki = 0; ki < 4; ++ki)
            bf[ki] = *(const f16x8*)(CW + (((L * 8 + wid) * 4 + ki) << 9) + lane * 8);
#pragma unroll
        for (int mt = 0; mt < 2; ++mt) {
            f16x8 af[4];
#pragma unroll
            for (int ki = 0; ki < 4; ++ki)
                af[ki] = lds_rd8(Xin, mt * 16 + l16, ki * 64 + hi * 16);
            f32x4 acc = { bc, bc, bc, bc };
#pragma unroll
            for (int ki = 0; ki < 4; ++ki)
                acc = __builtin_amdgcn_mfma_f32_16x16x32_f16(af[ki], bf[ki], acc, 0, 0, 0);
            float pv = 0.f;
            if (t0pos >= 0) pv = posp[(t0pos + mt * 4 + hi) * 128 + mycol];
#pragma unroll
            for (int j = 0; j < 4; ++j)
                lds_wr1(Xout, mt * 16 + hi * 4 + j, mycol, (f16)(gelu_f(acc[j]) + pv));
        }
    };

    auto flushYH = [&](int tc) {
        int tau = tid >> 4, cw = tid & 15;
        f16x8 v = lds_rd8(YH, tau, cw * 16);
        *(f16x8*)(ys + (size_t)(tc + (tau >> 2)) * (B_ * H_) +
                  (size_t)(bb0 + (tau & 3)) * H_ + cw * 8) = v;
    };

    for (int t0 = 0; t0 < T_; t0 += CH_) {
        // --- P0: conv layer0 (token tau = it*4 + r0) + prev-chunk ys flush ---
        {
            const float2* sp0 = (const float2*)src + ((size_t)(bb0 + r0) * T_ + t0) * 3;
#pragma unroll
            for (int it = 0; it < CH_; ++it) {
                float2 a = sp0[it * 3 + 0], b = sp0[it * 3 + 1], c2 = sp0[it * 3 + 2];
                float acc = b0c;
                acc = fmaf(a.x, w0c[0], acc);
                acc = fmaf(a.y, w0c[1], acc);
                acc = fmaf(b.x, w0c[2], acc);
                acc = fmaf(b.y, w0c[3], acc);
                acc = fmaf(c2.x, w0c[4], acc);
                acc = fmaf(c2.y, w0c[5], acc);
                lds_wr1(XA0, it * 4 + r0, col0, (f16)gelu_f(acc));
            }
        }
        if (t0 > 0) flushYH(t0 - CH_);
        __syncthreads();
        // --- P1..P3: conv layers 1..3 (dense 2x M16 tiles) ---
        conv_mfma(XA0, XA1, 0, b1c, -1);
        __syncthreads();
        conv_mfma(XA1, XA0, 1, b2c, -1);
        __syncthreads();
        conv_mfma(XA0, XA1, 2, b3c, t0);   // + pos_embed
        __syncthreads();
        // --- P4: z_x chunk GEMM: XA1 @ Wih^T -> ZX; B streamed from global ---
        {
            f16x8 af[2][4];
#pragma unroll
            for (int mt = 0; mt < 2; ++mt)
#pragma unroll
                for (int ki = 0; ki < 4; ++ki)
                    af[mt][ki] = lds_rd8(XA1, mt * 16 + l16, ki * 64 + hi * 16);
#pragma unroll
            for (int nt = 0; nt < 4; ++nt) {
                const int n = wid * 64 + nt * 16 + l16;
                f16x8 bf[4];
#pragma unroll
                for (int ki = 0; ki < 4; ++ki)
                    bf[ki] = load8cvt(Wih + n * 128 + ki * 32 + hi * 8);
                f32x4 za0 = { 0.f, 0.f, 0.f, 0.f };
                f32x4 za1 = { 0.f, 0.f, 0.f, 0.f };
#pragma unroll
                for (int ki = 0; ki < 4; ++ki) {
                    za0 = __builtin_amdgcn_mfma_f32_16x16x32_f16(af[0][ki], bf[ki], za0, 0, 0, 0);
                    za1 = __builtin_amdgcn_mfma_f32_16x16x32_f16(af[1][ki], bf[ki], za1, 0, 0, 0);
                }
#pragma unroll
                for (int j = 0; j < 4; ++j) {
                    zx_wr(ZX, hi * 4 + j, wid * 64 + nt * 16 + l16, (f16)za0[j]);
                    zx_wr(ZX, 16 + hi * 4 + j, wid * 64 + nt * 16 + l16, (f16)za1[j]);
                }
                __builtin_amdgcn_sched_barrier(0);  // keep per-nt loads from hoisting
            }
        }
        __syncthreads();
        // --- P5: 8 LSTM steps (h-side only on critical path) ---
        for (int it = 0; it < CH_; ++it) {
            const int t = t0 + it;
            f16x8 ha[4];
#pragma unroll
            for (int ki = 0; ki < 4; ++ki)
                ha[ki] = lds_rd8(HL[t & 1], l16 >> 2, ki * 64 + hi * 16);
            f32x4 acc[4];
#pragma unroll
            for (int g = 0; g < 4; ++g) {
                f32x4 bv = { biasg[g], biasg[g], biasg[g], biasg[g] };
                acc[g] = bv;
            }
#pragma unroll
            for (int ki = 0; ki < 4; ++ki)
#pragma unroll
                for (int g = 0; g < 4; ++g)
                    acc[g] = __builtin_amdgcn_mfma_f32_16x16x32_f16(ha[ki], whh[g][ki], acc[g], 0, 0, 0);
            float zi = acc[0][0] + zx_rd(ZX, it * 4 + hi, 0 + mycol);
            float zf = acc[1][0] + zx_rd(ZX, it * 4 + hi, 128 + mycol);
            float zg = acc[2][0] + zx_rd(ZX, it * 4 + hi, 256 + mycol);
            float zo = acc[3][0] + zx_rd(ZX, it * 4 + hi, 384 + mycol);
            c = sig_f(zf) * c + sig_f(zi) * tanh_f(zg);
            h = sig_f(zo) * tanh_f(c);
            lds_wr1(HL[(t + 1) & 1], hi, mycol, (f16)h);
            lds_wr1(YH, it * 4 + hi, mycol, (f16)h);
            __syncthreads();
        }
    }
    flushYH(T_ - CH_);
}

// ---------------------------------------------------------------------------
// K2: LSTM layer 1, CHUNKED. 256 blocks x 512 threads, 4 batch rows/block.
// Per 8-step chunk: 1 zgemm phase (A = ys chunk read coalesced from global,
// B = Wih1 streamed per-nt exactly like K1's P4) + 8 light slots (16 h-side
// MFMAs + pointwise; zx scalar reads from LDS). whh1 is the single resident
// fragment matrix (64 AGPR) — inside the proven budget. 576 phases vs old
// 512 heavier phases (32 MFMA + global x loads per slot).
// ---------------------------------------------------------------------------
__global__ __launch_bounds__(512) void lstm1_chunk_k(
    const f16* __restrict__ ys,
    const float* __restrict__ Wih, const float* __restrict__ Whh,
    const float* __restrict__ bih, const float* __restrict__ bhh,
    float* __restrict__ hfin)
{
    __shared__ f16 ZX[32 * 512];          // 32KB z_x chunk
    __shared__ f16 HL[2][4 * 128];        // 2KB h double-buffer

    const int tid = threadIdx.x;
    const int lane = tid & 63, wid = tid >> 6;
    const int l16 = lane & 15, hi = lane >> 4;
    const int bb0 = blockIdx.x * 4;
    const int mycol = wid * 16 + l16;

    f16x8 whh[4][4];
    float biasg[4];
#pragma unroll
    for (int g = 0; g < 4; ++g) {
        int n = g * 128 + mycol;
        biasg[g] = bih[n] + bhh[n];
#pragma unroll
        for (int ki = 0; ki < 4; ++ki)
            whh[g][ki] = load8cvt(Whh + n * 128 + ki * 32 + hi * 8);
    }
    for (int i = tid; i < 2 * 4 * 128; i += 512) ((f16*)HL)[i] = (f16)0.f;

    float c = 0.f, h = 0.f;
    __syncthreads();

    for (int t0 = 0; t0 < T_; t0 += CH_) {
        // --- zgemm: ZX = ys_chunk @ Wih^T (A from global, coalesced) ---
        {
            f16x8 af[2][4];
#pragma unroll
            for (int mt = 0; mt < 2; ++mt) {
                const int tau = mt * 16 + l16;
                const f16* ap = ys + (size_t)(t0 + (tau >> 2)) * (B_ * H_) +
                                (size_t)(bb0 + (tau & 3)) * H_;
#pragma unroll
                for (int ki = 0; ki < 4; ++ki)
                    af[mt][ki] = *(const f16x8*)(ap + ki * 32 + hi * 8);
            }
#pragma unroll
            for (int nt = 0; nt < 4; ++nt) {
                const int n = wid * 64 + nt * 16 + l16;
                f16x8 bf[4];
#pragma unroll
                for (int ki = 0; ki < 4; ++ki)
                    bf[ki] = load8cvt(Wih + n * 128 + ki * 32 + hi * 8);
                f32x4 za0 = { 0.f, 0.f, 0.f, 0.f };
                f32x4 za1 = { 0.f, 0.f, 0.f, 0.f };
#pragma unroll
                for (int ki = 0; ki < 4; ++ki) {
                    za0 = __builtin_amdgcn_mfma_f32_16x16x32_f16(af[0][ki], bf[ki], za0, 0, 0, 0);
                    za1 = __builtin_amdgcn_mfma_f32_16x16x32_f16(af[1][ki], bf[ki], za1, 0, 0, 0);
                }
#pragma unroll
                for (int j = 0; j < 4; ++j) {
                    zx_wr(ZX, hi * 4 + j, wid * 64 + nt * 16 + l16, (f16)za0[j]);
                    zx_wr(ZX, 16 + hi * 4 + j, wid * 64 + nt * 16 + l16, (f16)za1[j]);
                }
                __builtin_amdgcn_sched_barrier(0);
            }
        }
        __syncthreads();
        // --- 8 light LSTM slots ---
        for (int it = 0; it < CH_; ++it) {
            const int t = t0 + it;
            f16x8 ha[4];
#pragma unroll
            for (int ki = 0; ki < 4; ++ki)
                ha[ki] = lds_rd8(HL[t & 1], l16 >> 2, ki * 64 + hi * 16);
            f32x4 acc[4];
#pragma unroll
            for (int g = 0; g < 4; ++g) {
                f32x4 bv = { biasg[g], biasg[g], biasg[g], biasg[g] };
                acc[g] = bv;
            }
#pragma unroll
            for (int ki = 0; ki < 4; ++ki)
#pragma unroll
                for (int g = 0; g < 4; ++g)
                    acc[g] = __builtin_amdgcn_mfma_f32_16x16x32_f16(ha[ki], whh[g][ki], acc[g], 0, 0, 0);
            float zi = acc[0][0] + zx_rd(ZX, it * 4 + hi, 0 + mycol);
            float zf = acc[1][0] + zx_rd(ZX, it * 4 + hi, 128 + mycol);
            float zg = acc[2][0] + zx_rd(ZX, it * 4 + hi, 256 + mycol);
            float zo = acc[3][0] + zx_rd(ZX, it * 4 + hi, 384 + mycol);
            c = sig_f(zf) * c + sig_f(zi) * tanh_f(zg);
            h = sig_f(zo) * tanh_f(c);
            lds_wr1(HL[(t + 1) & 1], hi, mycol, (f16)h);
            __syncthreads();
        }
    }
    hfin[(size_t)(bb0 + hi) * H_ + mycol] = h;
}

// ---------------------------------------------------------------------------
// K3: head — LayerNorm + Linear(128->32) + GELU + Linear(32->8). 4 rows/block.
// ---------------------------------------------------------------------------
__global__ __launch_bounds__(256) void head_k(
    const float* __restrict__ hfin,
    const float* __restrict__ lng, const float* __restrict__ lnb,
    const float* __restrict__ hw1, const float* __restrict__ hb1,
    const float* __restrict__ hw2, const float* __restrict__ hb2,
    float* __restrict__ outp)
{
    __shared__ float HN[4][128];
    __shared__ float G[4][32];
    const int tid = threadIdx.x, lane = tid & 63, wid = tid >> 6;
    const int b = blockIdx.x * 4 + wid;
    float v0 = hfin[b * 128 + lane], v1 = hfin[b * 128 + 64 + lane];
    float s = v0 + v1;
#pragma unroll
    for (int m = 1; m < 64; m <<= 1) s += __shfl_xor(s, m);
    float mu = s * (1.f / 128.f);
    float d0 = v0 - mu, d1 = v1 - mu;
    float q = d0 * d0 + d1 * d1;
#pragma unroll
    for (int m = 1; m < 64; m <<= 1) q += __shfl_xor(q, m);
    float rs = rsqrtf(q * (1.f / 128.f) + 1e-5f);
    HN[wid][lane] = d0 * rs * lng[lane] + lnb[lane];
    HN[wid][64 + lane] = d1 * rs * lng[64 + lane] + lnb[64 + lane];
    __syncthreads();
    if (tid < 128) {
        int row = tid >> 5, o = tid & 31;
        float a = hb1[o];
#pragma unroll 4
        for (int k = 0; k < 128; ++k) a = fmaf(HN[row][k], hw1[o * 128 + k], a);
        G[row][o] = gelu_f(a);
    }
    __syncthreads();
    if (tid < 32) {
        int row = tid >> 3, oo = tid & 7;
        float a = hb2[oo];
#pragma unroll
        for (int k = 0; k < 32; ++k) a = fmaf(G[row][k], hw2[oo * 32 + k], a);
        outp[(size_t)(blockIdx.x * 4 + row) * 8 + oo] = a;
    }
}

extern "C" void kernel_launch(void* const* d_in, const int* in_sizes, int n_in,
                              void* d_out, int out_size, void* d_ws, size_t ws_size,
                              hipStream_t stream) {
    (void)in_sizes; (void)n_in; (void)out_size; (void)ws_size;
    const float* src  = (const float*)d_in[0];
    const float* w0   = (const float*)d_in[1];
    const float* b0   = (const float*)d_in[2];
    const float* w1   = (const float*)d_in[3];
    const float* b1   = (const float*)d_in[4];
    const float* w2   = (const float*)d_in[5];
    const float* b2   = (const float*)d_in[6];
    const float* w3   = (const float*)d_in[7];
    const float* b3   = (const float*)d_in[8];
    const float* pos  = (const float*)d_in[9];
    const float* Wih0 = (const float*)d_in[10];
    const float* Whh0 = (const float*)d_in[11];
    const float* bih0 = (const float*)d_in[12];
    const float* bhh0 = (const float*)d_in[13];
    const float* Wih1 = (const float*)d_in[14];
    const float* Whh1 = (const float*)d_in[15];
    const float* bih1 = (const float*)d_in[16];
    const float* bhh1 = (const float*)d_in[17];
    const float* lng  = (const float*)d_in[18];
    const float* lnb  = (const float*)d_in[19];
    const float* hw1  = (const float*)d_in[20];
    const float* hb1  = (const float*)d_in[21];
    const float* hw2  = (const float*)d_in[22];
    const float* hb2  = (const float*)d_in[23];
    float* outp = (float*)d_out;

    f16* ysbuf = (f16*)d_ws;                                 // (T,B,H) f16 = 128 MB
    float* hfin = (float*)((char*)d_ws + (size_t)134217728); // (B,H) f32

    fused_conv_lstm0_k<<<dim3(256), dim3(512), 0, stream>>>(
        src, w0, b0, w1, b1, w2, b2, w3, b3, pos,
        Wih0, Whh0, bih0, bhh0, ysbuf);
    lstm1_chunk_k<<<dim3(256), dim3(512), 0, stream>>>(
        ysbuf, Wih1, Whh1, bih1, bhh1, hfin);
    head_k<<<dim3(256), dim3(256), 0, stream>>>(
        hfin, lng, lnb, hw1, hb1, hw2, hb2, outp);
}

// Round 13
// 1061.974 us; speedup vs baseline: 4.7298x; 1.0279x over previous
//
#include <hip/hip_runtime.h>
#include <hip/hip_bf16.h>
#include <cstdint>

#define T_ 512
#define B_ 1024
#define D_ 6
#define H_ 128
#define CH_ 8   // chunk timesteps in lstm kernels
#define CT_ 16  // timesteps per conv block

typedef _Float16 f16;
typedef _Float16 f16x8 __attribute__((ext_vector_type(8)));
typedef float f32x4 __attribute__((ext_vector_type(4)));

// branch-free erf (Abramowitz-Stegun 7.1.26, max abs err 1.5e-7)
__device__ __forceinline__ float erf_f(float x) {
    float ax = fabsf(x);
    float t = __builtin_amdgcn_rcpf(fmaf(0.3275911f, ax, 1.f));
    float p = fmaf(t, 1.061405429f, -1.453152027f);
    p = fmaf(t, p, 1.421413741f);
    p = fmaf(t, p, -0.284496736f);
    p = fmaf(t, p, 0.254829592f);
    p = p * t;
    float e = __builtin_amdgcn_exp2f(-ax * ax * 1.4426950408889634f);
    float r = 1.f - p * e;
    return copysignf(r, x);
}
__device__ __forceinline__ float gelu_f(float x) {
    return 0.5f * x * (1.f + erf_f(x * 0.7071067811865476f));
}
__device__ __forceinline__ float sig_f(float x) {
    return __builtin_amdgcn_rcpf(1.f + __builtin_amdgcn_exp2f(-1.4426950408889634f * x));
}
__device__ __forceinline__ float tanh_f(float x) {
    return 2.f * sig_f(2.f * x) - 1.f;
}
__device__ __forceinline__ f16x8 load8cvt(const float* p) {
    float4 a = ((const float4*)p)[0];
    float4 b = ((const float4*)p)[1];
    f16x8 r = { (f16)a.x, (f16)a.y, (f16)a.z, (f16)a.w,
                (f16)b.x, (f16)b.y, (f16)b.z, (f16)b.w };
    return r;
}
// LDS tiles: row-major [rows][128] f16, 256B row stride, 16B-chunk XOR swizzle
__device__ __forceinline__ f16x8 lds_rd8(const f16* base, int row, int cb) {
    const char* p = (const char*)base + row * 256 + (cb ^ ((row & 7) << 4));
    return *(const f16x8*)p;
}
__device__ __forceinline__ void lds_wr1(f16* base, int row, int col, f16 v) {
    char* p = (char*)base + row * 256 + ((col * 2) ^ ((row & 7) << 4));
    *(f16*)p = v;
}
// ZX tile: [32 rows][512 cols] f16, 1024B row stride, same XOR swizzle
__device__ __forceinline__ void zx_wr(f16* base, int row, int col, f16 v) {
    char* p = (char*)base + row * 1024 + ((col * 2) ^ ((row & 7) << 4));
    *(f16*)p = v;
}
__device__ __forceinline__ float zx_rd(const f16* base, int row, int col) {
    const char* p = (const char*)base + row * 1024 + ((col * 2) ^ ((row & 7) << 4));
    return (float)*(const f16*)p;
}

// ---------------------------------------------------------------------------
// K1: conv stack STANDALONE — embarrassingly parallel over tokens (pulled out
// of the recurrence loop, where each conv phase cost ~4k cyc serialized).
// 8192 blocks x 512 thr; block = 4 batch rows x 16 timesteps = 64 tokens
// (4 dense M-tiles). Straight-line, 5 phases, no loop -> no LICM hazard;
// conv weights in 48 resident frag regs. Writes x (T,B,H) f16 coalesced.
// ---------------------------------------------------------------------------
__global__ __launch_bounds__(512) void conv_k(
    const float* __restrict__ src,
    const float* __restrict__ w0p, const float* __restrict__ b0p,
    const float* __restrict__ w1p, const float* __restrict__ b1p,
    const float* __restrict__ w2p, const float* __restrict__ b2p,
    const float* __restrict__ w3p, const float* __restrict__ b3p,
    const float* __restrict__ posp, f16* __restrict__ xout)
{
    __shared__ f16 XA0[64 * 128];   // 16KB
    __shared__ f16 XA1[64 * 128];   // 16KB
    const int tid = threadIdx.x;
    const int lane = tid & 63, wid = tid >> 6;
    const int l16 = lane & 15, hi = lane >> 4;
    const int t0 = (blockIdx.x & 31) * CT_;
    const int bb0 = (blockIdx.x >> 5) * 4;
    const int mycol = wid * 16 + l16;

    // resident conv B-frags (48 VGPRs) — straight-line kernel, no spill risk
    f16x8 cw[3][4];
    {
        const float* wp[3] = { w1p, w2p, w3p };
#pragma unroll
        for (int L = 0; L < 3; ++L)
#pragma unroll
            for (int ki = 0; ki < 4; ++ki)
                cw[L][ki] = load8cvt(wp[L] + mycol * 128 + ki * 32 + hi * 8);
    }
    const int col0 = tid & 127;
    const int r0 = tid >> 7;
    float w0c[6], b0c;
#pragma unroll
    for (int k = 0; k < 6; ++k) w0c[k] = w0p[col0 * 6 + k];
    b0c = b0p[col0];
    const float b1c = b1p[mycol], b2c = b2p[mycol], b3c = b3p[mycol];

    // P0: conv layer0 (VALU), 16 timesteps -> XA0 rows it*4+r0
    {
        const float2* sp0 = (const float2*)src + ((size_t)(bb0 + r0) * T_ + t0) * 3;
#pragma unroll
        for (int it = 0; it < CT_; ++it) {
            float2 a = sp0[it * 3 + 0], b = sp0[it * 3 + 1], c2 = sp0[it * 3 + 2];
            float acc = b0c;
            acc = fmaf(a.x, w0c[0], acc);
            acc = fmaf(a.y, w0c[1], acc);
            acc = fmaf(b.x, w0c[2], acc);
            acc = fmaf(b.y, w0c[3], acc);
            acc = fmaf(c2.x, w0c[4], acc);
            acc = fmaf(c2.y, w0c[5], acc);
            lds_wr1(XA0, it * 4 + r0, col0, (f16)gelu_f(acc));
        }
    }
    __syncthreads();

    // P1..P3: conv layers 1..3, 4 dense M-tiles each
    auto conv_mfma = [&](const f16* Xin, f16* Xout, int L, float bc, bool addpos) {
#pragma unroll
        for (int mt = 0; mt < 4; ++mt) {
            f16x8 af[4];
#pragma unroll
            for (int ki = 0; ki < 4; ++ki)
                af[ki] = lds_rd8(Xin, mt * 16 + l16, ki * 64 + hi * 16);
            f32x4 acc = { bc, bc, bc, bc };
#pragma unroll
            for (int ki = 0; ki < 4; ++ki)
                acc = __builtin_amdgcn_mfma_f32_16x16x32_f16(af[ki], cw[L][ki], acc, 0, 0, 0);
            float pv = 0.f;
            if (addpos) pv = posp[(t0 + mt * 4 + hi) * 128 + mycol];
#pragma unroll
            for (int j = 0; j < 4; ++j)
                lds_wr1(Xout, mt * 16 + hi * 4 + j, mycol, (f16)(gelu_f(acc[j]) + pv));
        }
    };
    conv_mfma(XA0, XA1, 0, b1c, false);
    __syncthreads();
    conv_mfma(XA1, XA0, 1, b2c, false);
    __syncthreads();
    conv_mfma(XA0, XA1, 2, b3c, true);   // + pos_embed
    __syncthreads();

    // flush XA1 -> x (coalesced f16x8; 1024 units over 512 threads)
#pragma unroll
    for (int pass = 0; pass < 2; ++pass) {
        int u = pass * 512 + tid;
        int tau = u >> 4, cw8 = u & 15;
        f16x8 v = lds_rd8(XA1, tau, cw8 * 16);
        *(f16x8*)(xout + (size_t)(t0 + (tau >> 2)) * (B_ * H_) +
                  (size_t)(bb0 + (tau & 3)) * H_ + cw8 * 8) = v;
    }
}

// ---------------------------------------------------------------------------
// K2/K3: one LSTM layer, CHUNKED (proven lstm1_chunk structure, 280us).
// 256 blocks x 512 thr, 4 rows/block. Per 8-step chunk: 1 zgemm phase
// (A = x chunk read coalesced from global, B = Wih streamed per-nt) +
// 8 light slots (16 h-side MFMA + in-register pointwise). whh = the single
// resident frag matrix (64 regs, AGPR-side) — proven budget.
// WRITE_YS: lstm0 — h history -> YH, flushed IN PLACE over x (x[t] is dead
// after its chunk's zgemm; saves 128MB ws + keeps L3 warm).
// WRITE_H: lstm1 — final h -> hfin.
// ---------------------------------------------------------------------------
template <bool WRITE_YS, bool WRITE_H>
__global__ __launch_bounds__(512) void lstm_chunk_k(
    const f16* __restrict__ xb,
    const float* __restrict__ Wih, const float* __restrict__ Whh,
    const float* __restrict__ bih, const float* __restrict__ bhh,
    f16* __restrict__ ys, float* __restrict__ hfin)
{
    __shared__ f16 ZX[32 * 512];          // 32KB z_x chunk
    __shared__ f16 YH[32 * 128];          // 8KB h history (WRITE_YS only)
    __shared__ f16 HL[2][4 * 128];        // 2KB h double-buffer

    const int tid = threadIdx.x;
    const int lane = tid & 63, wid = tid >> 6;
    const int l16 = lane & 15, hi = lane >> 4;
    const int bb0 = blockIdx.x * 4;
    const int mycol = wid * 16 + l16;

    f16x8 whh[4][4];
    float biasg[4];
#pragma unroll
    for (int g = 0; g < 4; ++g) {
        int n = g * 128 + mycol;
        biasg[g] = bih[n] + bhh[n];
#pragma unroll
        for (int ki = 0; ki < 4; ++ki)
            whh[g][ki] = load8cvt(Whh + n * 128 + ki * 32 + hi * 8);
    }
    for (int i = tid; i < 2 * 4 * 128; i += 512) ((f16*)HL)[i] = (f16)0.f;

    float c = 0.f, h = 0.f;
    __syncthreads();

    auto flushYH = [&](int tc) {
        int tau = tid >> 4, cw8 = tid & 15;
        f16x8 v = lds_rd8(YH, tau, cw8 * 16);
        *(f16x8*)(ys + (size_t)(tc + (tau >> 2)) * (B_ * H_) +
                  (size_t)(bb0 + (tau & 3)) * H_ + cw8 * 8) = v;
    };

    for (int t0 = 0; t0 < T_; t0 += CH_) {
        // --- zgemm phase: flush prev YH (WRITE_YS), then ZX = x_chunk @ Wih^T
        if (WRITE_YS && t0 > 0) flushYH(t0 - CH_);
        {
            f16x8 af[2][4];
#pragma unroll
            for (int mt = 0; mt < 2; ++mt) {
                const int tau = mt * 16 + l16;
                const f16* ap = xb + (size_t)(t0 + (tau >> 2)) * (B_ * H_) +
                                (size_t)(bb0 + (tau & 3)) * H_;
#pragma unroll
                for (int ki = 0; ki < 4; ++ki)
                    af[mt][ki] = *(const f16x8*)(ap + ki * 32 + hi * 8);
            }
#pragma unroll
            for (int nt = 0; nt < 4; ++nt) {
                const int n = wid * 64 + nt * 16 + l16;
                f16x8 bf[4];
#pragma unroll
                for (int ki = 0; ki < 4; ++ki)
                    bf[ki] = load8cvt(Wih + n * 128 + ki * 32 + hi * 8);
                f32x4 za0 = { 0.f, 0.f, 0.f, 0.f };
                f32x4 za1 = { 0.f, 0.f, 0.f, 0.f };
#pragma unroll
                for (int ki = 0; ki < 4; ++ki) {
                    za0 = __builtin_amdgcn_mfma_f32_16x16x32_f16(af[0][ki], bf[ki], za0, 0, 0, 0);
                    za1 = __builtin_amdgcn_mfma_f32_16x16x32_f16(af[1][ki], bf[ki], za1, 0, 0, 0);
                }
#pragma unroll
                for (int j = 0; j < 4; ++j) {
                    zx_wr(ZX, hi * 4 + j, wid * 64 + nt * 16 + l16, (f16)za0[j]);
                    zx_wr(ZX, 16 + hi * 4 + j, wid * 64 + nt * 16 + l16, (f16)za1[j]);
                }
                __builtin_amdgcn_sched_barrier(0);
            }
        }
        __syncthreads();
        // --- 8 light LSTM slots ---
        for (int it = 0; it < CH_; ++it) {
            const int t = t0 + it;
            f16x8 ha[4];
#pragma unroll
            for (int ki = 0; ki < 4; ++ki)
                ha[ki] = lds_rd8(HL[t & 1], l16 >> 2, ki * 64 + hi * 16);
            f32x4 acc[4];
#pragma unroll
            for (int g = 0; g < 4; ++g) {
                f32x4 bv = { biasg[g], biasg[g], biasg[g], biasg[g] };
                acc[g] = bv;
            }
#pragma unroll
            for (int ki = 0; ki < 4; ++ki)
#pragma unroll
                for (int g = 0; g < 4; ++g)
                    acc[g] = __builtin_amdgcn_mfma_f32_16x16x32_f16(ha[ki], whh[g][ki], acc[g], 0, 0, 0);
            float zi = acc[0][0] + zx_rd(ZX, it * 4 + hi, 0 + mycol);
            float zf = acc[1][0] + zx_rd(ZX, it * 4 + hi, 128 + mycol);
            float zg = acc[2][0] + zx_rd(ZX, it * 4 + hi, 256 + mycol);
            float zo = acc[3][0] + zx_rd(ZX, it * 4 + hi, 384 + mycol);
            c = sig_f(zf) * c + sig_f(zi) * tanh_f(zg);
            h = sig_f(zo) * tanh_f(c);
            lds_wr1(HL[(t + 1) & 1], hi, mycol, (f16)h);
            if (WRITE_YS) lds_wr1(YH, it * 4 + hi, mycol, (f16)h);
            __syncthreads();
        }
    }
    if (WRITE_YS) flushYH(T_ - CH_);
    if (WRITE_H) hfin[(size_t)(bb0 + hi) * H_ + mycol] = h;
}

// ---------------------------------------------------------------------------
// K4: head — LayerNorm + Linear(128->32) + GELU + Linear(32->8). 4 rows/block.
// ---------------------------------------------------------------------------
__global__ __launch_bounds__(256) void head_k(
    const float* __restrict__ hfin,
    const float* __restrict__ lng, const float* __restrict__ lnb,
    const float* __restrict__ hw1, const float* __restrict__ hb1,
    const float* __restrict__ hw2, const float* __restrict__ hb2,
    float* __restrict__ outp)
{
    __shared__ float HN[4][128];
    __shared__ float G[4][32];
    const int tid = threadIdx.x, lane = tid & 63, wid = tid >> 6;
    const int b = blockIdx.x * 4 + wid;
    float v0 = hfin[b * 128 + lane], v1 = hfin[b * 128 + 64 + lane];
    float s = v0 + v1;
#pragma unroll
    for (int m = 1; m < 64; m <<= 1) s += __shfl_xor(s, m);
    float mu = s * (1.f / 128.f);
    float d0 = v0 - mu, d1 = v1 - mu;
    float q = d0 * d0 + d1 * d1;
#pragma unroll
    for (int m = 1; m < 64; m <<= 1) q += __shfl_xor(q, m);
    float rs = rsqrtf(q * (1.f / 128.f) + 1e-5f);
    HN[wid][lane] = d0 * rs * lng[lane] + lnb[lane];
    HN[wid][64 + lane] = d1 * rs * lng[64 + lane] + lnb[64 + lane];
    __syncthreads();
    if (tid < 128) {
        int row = tid >> 5, o = tid & 31;
        float a = hb1[o];
#pragma unroll 4
        for (int k = 0; k < 128; ++k) a = fmaf(HN[row][k], hw1[o * 128 + k], a);
        G[row][o] = gelu_f(a);
    }
    __syncthreads();
    if (tid < 32) {
        int row = tid >> 3, oo = tid & 7;
        float a = hb2[oo];
#pragma unroll
        for (int k = 0; k < 32; ++k) a = fmaf(G[row][k], hw2[oo * 32 + k], a);
        outp[(size_t)(blockIdx.x * 4 + row) * 8 + oo] = a;
    }
}

extern "C" void kernel_launch(void* const* d_in, const int* in_sizes, int n_in,
                              void* d_out, int out_size, void* d_ws, size_t ws_size,
                              hipStream_t stream) {
    (void)in_sizes; (void)n_in; (void)out_size; (void)ws_size;
    const float* src  = (const float*)d_in[0];
    const float* w0   = (const float*)d_in[1];
    const float* b0   = (const float*)d_in[2];
    const float* w1   = (const float*)d_in[3];
    const float* b1   = (const float*)d_in[4];
    const float* w2   = (const float*)d_in[5];
    const float* b2   = (const float*)d_in[6];
    const float* w3   = (const float*)d_in[7];
    const float* b3   = (const float*)d_in[8];
    const float* pos  = (const float*)d_in[9];
    const float* Wih0 = (const float*)d_in[10];
    const float* Whh0 = (const float*)d_in[11];
    const float* bih0 = (const float*)d_in[12];
    const float* bhh0 = (const float*)d_in[13];
    const float* Wih1 = (const float*)d_in[14];
    const float* Whh1 = (const float*)d_in[15];
    const float* bih1 = (const float*)d_in[16];
    const float* bhh1 = (const float*)d_in[17];
    const float* lng  = (const float*)d_in[18];
    const float* lnb  = (const float*)d_in[19];
    const float* hw1  = (const float*)d_in[20];
    const float* hb1  = (const float*)d_in[21];
    const float* hw2  = (const float*)d_in[22];
    const float* hb2  = (const float*)d_in[23];
    float* outp = (float*)d_out;

    f16* xbuf = (f16*)d_ws;                                  // (T,B,H) f16 = 128 MB
    float* hfin = (float*)((char*)d_ws + (size_t)134217728); // (B,H) f32

    conv_k<<<dim3(8192), dim3(512), 0, stream>>>(
        src, w0, b0, w1, b1, w2, b2, w3, b3, pos, xbuf);
    lstm_chunk_k<true, false><<<dim3(256), dim3(512), 0, stream>>>(
        xbuf, Wih0, Whh0, bih0, bhh0, xbuf, nullptr);        // ys in-place over x
    lstm_chunk_k<false, true><<<dim3(256), dim3(512), 0, stream>>>(
        xbuf, Wih1, Whh1, bih1, bhh1, nullptr, hfin);
    head_k<<<dim3(256), dim3(256), 0, stream>>>(
        hfin, lng, lnb, hw1, hb1, hw2, hb2, outp);
}